// Round 4
// baseline (112.928 us; speedup 1.0000x reference)
//
#include <hip/hip_runtime.h>

// Discounted cumsum y[t] = x[t] + gamma[h]*y[t-1] along S.
// x:(B,H,S,D)=(8,16,4096,128) fp32, gamma:(H,)
// Single-pass decoupled-lookback scan:
//   block = (bh, S-chunk of 256 timesteps), FULL D (contiguous 128 KB stream)
//   512 threads: d4c=tid&31 (float4 col), tg=tid>>5 (16 groups x 16 t)
//   local reg scan -> 1-step shfl scan (2 tgs/wave) -> LDS 8-wave combine
//   -> wave0 lookback via packed (value,flag) 64-bit atomics in d_ws
//   -> apply prefix, store. Ticket-ordered block ids for deadlock freedom.

namespace {
constexpr int kH      = 16;
constexpr int kBH     = 128;            // B*H
constexpr int kS      = 4096;
constexpr int kD4     = 32;             // float4 per row (D=128)
constexpr int kThreads = 512;           // 8 waves
constexpr int kJ      = 16;             // timesteps per thread
constexpr int kTGs    = kThreads / 32;  // 16 thread-groups
constexpr int kCk     = kJ * kTGs;      // 256 timesteps per chunk
constexpr int kSC     = kS / kCk;       // 16 chunks per bh
constexpr int kBlocks = kBH * kSC;      // 2048
constexpr int kElems  = 128;            // carry floats per boundary (D)
constexpr unsigned long long kFlagAgg = 1ULL << 32;
constexpr unsigned long long kFlagInc = 2ULL << 32;
constexpr size_t kPackCount = (size_t)kBH * kSC * kElems;  // 262144 packs
}

__device__ __forceinline__ unsigned long long packvf(float v, unsigned long long f) {
    return f | (unsigned long long)__float_as_uint(v);
}

__global__ __launch_bounds__(kThreads) void dscan_lookback(
    const float* __restrict__ x, const float* __restrict__ gamma,
    float* __restrict__ y, unsigned long long* __restrict__ ws)
{
    __shared__ float4 s_wsum[8][kD4];     // per-wave totals, per column
    __shared__ float4 s_carry4[kD4];      // chunk carry-in, per column
    __shared__ int s_ticket;

    if (threadIdx.x == 0) {
        unsigned* tk = (unsigned*)(ws + kPackCount);
        s_ticket = (int)atomicAdd(tk, 1u);
    }
    __syncthreads();
    const int ticket = s_ticket;
    const int sc = ticket >> 7;           // / kBH  -> chunk idx (globally ordered)
    const int bh = ticket & (kBH - 1);

    const int tid = (int)threadIdx.x;
    const int d4c = tid & 31;
    const int tg  = tid >> 5;             // 0..15
    const int wv  = tg >> 1;              // wave 0..7
    const int tgl = tg & 1;               // tg within wave

    const float g = gamma[bh & (kH - 1)];
    float gp[kJ];                         // gp[j] = g^(j+1)
    gp[0] = g;
    #pragma unroll
    for (int j = 1; j < kJ; ++j) gp[j] = gp[j - 1] * g;
    const float g16  = gp[kJ - 1];        // g^16  (per-thread span)
    const float g32  = g16 * g16;         // per-wave span (2 tgs)
    const float g64  = g32 * g32;
    const float g128 = g64 * g64;
    const float g256 = g128 * g128;       // per-chunk span
    // decay from chunk start to this thread's start: g^(16*tg)
    const float gA = ((tg & 1) ? g16 : 1.f) * ((tg & 2) ? g32 : 1.f) *
                     ((tg & 4) ? g64 : 1.f) * ((tg & 8) ? g128 : 1.f);
    const float gW = tgl ? g16 : 1.f;     // wave-start -> thread-start decay

    const float4* __restrict__ xv = reinterpret_cast<const float4*>(x);
    float4*       __restrict__ yv = reinterpret_cast<float4*>(y);
    const int base = (bh * kS + sc * kCk + tg * kJ) * kD4 + d4c;

    // ---- load 16 float4 (contiguous rows), local inclusive scan ----
    float4 v[kJ];
    #pragma unroll
    for (int j = 0; j < kJ; ++j) v[j] = xv[base + j * kD4];
    #pragma unroll
    for (int j = 1; j < kJ; ++j) {
        v[j].x = fmaf(g, v[j - 1].x, v[j].x);
        v[j].y = fmaf(g, v[j - 1].y, v[j].y);
        v[j].z = fmaf(g, v[j - 1].z, v[j].z);
        v[j].w = fmaf(g, v[j - 1].w, v[j].w);
    }

    // ---- intra-wave scan of thread totals (2 tgs, stride 32 lanes) ----
    float4 s = v[kJ - 1];
    {
        float tx = __shfl_up(s.x, 32, 64), ty = __shfl_up(s.y, 32, 64);
        float tz = __shfl_up(s.z, 32, 64), tw = __shfl_up(s.w, 32, 64);
        if (tgl == 1) {
            s.x = fmaf(g16, tx, s.x); s.y = fmaf(g16, ty, s.y);
            s.z = fmaf(g16, tz, s.z); s.w = fmaf(g16, tw, s.w);
        }
    }
    float4 X;                              // exclusive wave-local prefix
    X.x = __shfl_up(s.x, 32, 64); X.y = __shfl_up(s.y, 32, 64);
    X.z = __shfl_up(s.z, 32, 64); X.w = __shfl_up(s.w, 32, 64);
    if (tgl == 0) X = make_float4(0.f, 0.f, 0.f, 0.f);

    if (tgl == 1) s_wsum[wv][d4c] = s;     // wave total
    __syncthreads();

    // ---- combine earlier waves' totals (decay g32 per wave) ----
    float4 C = make_float4(0.f, 0.f, 0.f, 0.f);
    #pragma unroll
    for (int w2 = 0; w2 < 7; ++w2) {
        if (w2 < wv) {
            float4 W = s_wsum[w2][d4c];
            C.x = fmaf(g32, C.x, W.x); C.y = fmaf(g32, C.y, W.y);
            C.z = fmaf(g32, C.z, W.z); C.w = fmaf(g32, C.w, W.w);
        }
    }

    // ---- wave 0: decoupled lookback (lane owns 2 float columns) ----
    if (tid < 64) {
        unsigned long long* wsrow = ws + (size_t)bh * kSC * kElems;
        #pragma unroll
        for (int e = 0; e < 2; ++e) {
            const int d = tid * 2 + e;
            // block aggregate for column d: combine all 8 wave totals
            float Ed = 0.f;
            #pragma unroll
            for (int w = 0; w < 8; ++w)
                Ed = fmaf(g32, Ed, ((const float*)&s_wsum[w][d >> 2])[d & 3]);
            unsigned long long* slot = wsrow + sc * kElems + d;
            float Cin = 0.f;
            if (sc == 0) {
                atomicExch(slot, packvf(Ed, kFlagInc));
            } else {
                if (sc != kSC - 1) atomicExch(slot, packvf(Ed, kFlagAgg));
                float gpk = 1.f;
                int k = sc - 1;
                while (true) {
                    unsigned long long p = atomicAdd(wsrow + k * kElems + d, 0ULL);
                    unsigned st = (unsigned)(p >> 32);
                    if (st == 0u) continue;
                    float val = __uint_as_float((unsigned)p);
                    Cin = fmaf(gpk, val, Cin);
                    if (st == 2u) break;
                    gpk *= g256; --k;
                }
                if (sc != kSC - 1)
                    atomicExch(slot, packvf(fmaf(g256, Cin, Ed), kFlagInc));
            }
            ((float*)s_carry4)[d] = Cin;
        }
    }
    __syncthreads();

    // ---- apply prefix and store ----
    const float4 A = s_carry4[d4c];        // y at chunk_start - 1
    float4 E;                              // y at this thread's start - 1
    E.x = fmaf(gA, A.x, fmaf(gW, C.x, X.x));
    E.y = fmaf(gA, A.y, fmaf(gW, C.y, X.y));
    E.z = fmaf(gA, A.z, fmaf(gW, C.z, X.z));
    E.w = fmaf(gA, A.w, fmaf(gW, C.w, X.w));

    #pragma unroll
    for (int j = 0; j < kJ; ++j) {
        float4 o;
        o.x = fmaf(gp[j], E.x, v[j].x);
        o.y = fmaf(gp[j], E.y, v[j].y);
        o.z = fmaf(gp[j], E.z, v[j].z);
        o.w = fmaf(gp[j], E.w, v[j].w);
        yv[base + j * kD4] = o;
    }
}

extern "C" void kernel_launch(void* const* d_in, const int* in_sizes, int n_in,
                              void* d_out, int out_size, void* d_ws, size_t ws_size,
                              hipStream_t stream) {
    const float* x     = (const float*)d_in[0];
    const float* gamma = (const float*)d_in[1];
    float* y = (float*)d_out;
    unsigned long long* ws = (unsigned long long*)d_ws;
    // zero flags + ticket every launch (harness does not re-poison between replays)
    hipMemsetAsync(d_ws, 0, kPackCount * 8 + 16, stream);
    dscan_lookback<<<kBlocks, kThreads, 0, stream>>>(x, gamma, y, ws);
}

// Round 5
// 84.394 us; speedup vs baseline: 1.3381x; 1.3381x over previous
//
#include <hip/hip_runtime.h>

// Discounted cumsum y[t] = x[t] + gamma[h]*y[t-1] along S.
// x:(B,H,S,D)=(8,16,4096,128) fp32, gamma:(H,)
// Round-3 structure (single-pass serial S-walk, block = (bh, D-quarter),
// lgkm-only tile barrier) + ONE change: y stores are NON-TEMPORAL
// (global_store_dwordx4 nt) to avoid write-allocate/RFO and keep x
// resident in the 256MB L3 across timed replays.

namespace {
constexpr int kH     = 16;
constexpr int kBH    = 128;         // B*H
constexpr int kS     = 4096;
constexpr int kD4    = 32;          // float4 per row (D=128)
constexpr int kDQ4   = 8;           // float4 columns per block (quarter of D)
constexpr int kTG    = 32;          // thread-groups along t per tile
constexpr int kJ     = 8;           // timesteps per thread
constexpr int kTileT = kTG * kJ;    // 256 timesteps per tile
constexpr int kIters = kS / kTileT; // 16
constexpr int kThreads = kDQ4 * kTG; // 256
}

typedef float floatx4 __attribute__((ext_vector_type(4)));

__device__ __forceinline__ void nt_store4(float4* p, const float4& v) {
    floatx4 t;
    t.x = v.x; t.y = v.y; t.z = v.z; t.w = v.w;
    __builtin_nontemporal_store(t, reinterpret_cast<floatx4*>(p));
}

__global__ __launch_bounds__(kThreads) void dscan_kernel(
    const float* __restrict__ x, const float* __restrict__ gamma,
    float* __restrict__ y)
{
    const int bh = blockIdx.x >> 2;
    const int dq = blockIdx.x & 3;
    const int tid = (int)threadIdx.x;
    const int d4c = tid & (kDQ4 - 1);
    const int tg  = tid >> 3;        // 0..31 timestep group
    const int wv  = tg >> 3;         // wave id 0..3
    const int tgl = tg & 7;          // tg within wave

    const float g = gamma[bh & (kH - 1)];
    float gp[kJ];                    // gp[j] = g^(j+1)
    gp[0] = g;
    #pragma unroll
    for (int j = 1; j < kJ; ++j) gp[j] = gp[j - 1] * g;
    const float g8   = gp[kJ - 1];   // g^8
    const float g16  = g8 * g8;
    const float g32  = g16 * g16;
    const float g64  = g32 * g32;    // per-wave decay (8 tgs * 8 t)
    const float g128 = g64 * g64;
    // gtl = g^(8*tgl); g8tg = g^(8*tg)
    const float gtl = ((tgl & 1) ? g8 : 1.f) * ((tgl & 2) ? g16 : 1.f) *
                      ((tgl & 4) ? g32 : 1.f);
    const float g8tg = gtl * ((tg & 8) ? g64 : 1.f) * ((tg & 16) ? g128 : 1.f);

    __shared__ float4 s_wsum[2][4][kDQ4];   // [parity][wave][d4c]
    __shared__ float4 s_carry[2][kDQ4];     // [parity][d4c]
    if (tid < kDQ4) s_carry[0][tid] = make_float4(0.f, 0.f, 0.f, 0.f);
    __syncthreads();

    const float4* __restrict__ xv = reinterpret_cast<const float4*>(x);
    float4*       __restrict__ yv = reinterpret_cast<float4*>(y);
    const int base = bh * kS * kD4 + dq * kDQ4 + d4c;
    const int tb   = tg * kJ;

    float4 v[kJ], w[kJ];
    #pragma unroll
    for (int j = 0; j < kJ; ++j) v[j] = xv[base + (tb + j) * kD4];

    auto tile = [&](int it, float4 (&cv)[kJ], float4 (&nv)[kJ]) {
        const int p = it & 1;

        // local inclusive scan over this thread's 8 timesteps
        #pragma unroll
        for (int j = 1; j < kJ; ++j) {
            cv[j].x = fmaf(g, cv[j - 1].x, cv[j].x);
            cv[j].y = fmaf(g, cv[j - 1].y, cv[j].y);
            cv[j].z = fmaf(g, cv[j - 1].z, cv[j].z);
            cv[j].w = fmaf(g, cv[j - 1].w, cv[j].w);
        }

        // prefetch next tile (rides across the lgkm-only barrier)
        if (it + 1 < kIters) {
            const int nb = base + ((it + 1) * kTileT + tb) * kD4;
            #pragma unroll
            for (int j = 0; j < kJ; ++j) nv[j] = xv[nb + j * kD4];
        }

        // intra-wave inclusive scan of thread totals (8 tgs, stride 8 lanes)
        float4 s = cv[kJ - 1];
        {
            float tx = __shfl_up(s.x, 8, 64), ty = __shfl_up(s.y, 8, 64);
            float tz = __shfl_up(s.z, 8, 64), tw = __shfl_up(s.w, 8, 64);
            if (tgl >= 1) {
                s.x = fmaf(g8, tx, s.x); s.y = fmaf(g8, ty, s.y);
                s.z = fmaf(g8, tz, s.z); s.w = fmaf(g8, tw, s.w);
            }
        }
        {
            float tx = __shfl_up(s.x, 16, 64), ty = __shfl_up(s.y, 16, 64);
            float tz = __shfl_up(s.z, 16, 64), tw = __shfl_up(s.w, 16, 64);
            if (tgl >= 2) {
                s.x = fmaf(g16, tx, s.x); s.y = fmaf(g16, ty, s.y);
                s.z = fmaf(g16, tz, s.z); s.w = fmaf(g16, tw, s.w);
            }
        }
        {
            float tx = __shfl_up(s.x, 32, 64), ty = __shfl_up(s.y, 32, 64);
            float tz = __shfl_up(s.z, 32, 64), tw = __shfl_up(s.w, 32, 64);
            if (tgl >= 4) {
                s.x = fmaf(g32, tx, s.x); s.y = fmaf(g32, ty, s.y);
                s.z = fmaf(g32, tz, s.z); s.w = fmaf(g32, tw, s.w);
            }
        }
        // exclusive wave-local prefix at this thread's start-1
        float4 X;
        X.x = __shfl_up(s.x, 8, 64); X.y = __shfl_up(s.y, 8, 64);
        X.z = __shfl_up(s.z, 8, 64); X.w = __shfl_up(s.w, 8, 64);
        if (tgl == 0) X = make_float4(0.f, 0.f, 0.f, 0.f);

        if (tgl == 7) s_wsum[p][wv][d4c] = s;   // wave total per column

        // LDS-only drain + barrier: vmem ops stay in flight
        asm volatile("s_waitcnt lgkmcnt(0)\n\ts_barrier" ::: "memory");

        // combine earlier waves' totals (decay g64 per wave)
        float4 C = make_float4(0.f, 0.f, 0.f, 0.f);
        #pragma unroll
        for (int w2 = 0; w2 < 3; ++w2) {
            if (w2 < wv) {
                float4 W = s_wsum[p][w2][d4c];
                C.x = fmaf(g64, C.x, W.x); C.y = fmaf(g64, C.y, W.y);
                C.z = fmaf(g64, C.z, W.z); C.w = fmaf(g64, C.w, W.w);
            }
        }
        const float4 A = s_carry[p][d4c];       // y at tile_start - 1
        float4 E;                               // y at this thread's start-1
        E.x = fmaf(g8tg, A.x, fmaf(gtl, C.x, X.x));
        E.y = fmaf(g8tg, A.y, fmaf(gtl, C.y, X.y));
        E.z = fmaf(g8tg, A.z, fmaf(gtl, C.z, X.z));
        E.w = fmaf(g8tg, A.w, fmaf(gtl, C.w, X.w));

        // apply prefix and store (non-temporal: no allocate, no RFO)
        const int ob = base + (it * kTileT + tb) * kD4;
        #pragma unroll
        for (int j = 0; j < kJ; ++j) {
            float4 o;
            o.x = fmaf(gp[j], E.x, cv[j].x);
            o.y = fmaf(gp[j], E.y, cv[j].y);
            o.z = fmaf(gp[j], E.z, cv[j].z);
            o.w = fmaf(gp[j], E.w, cv[j].w);
            nt_store4(&yv[ob + j * kD4], o);
            if (j == kJ - 1 && tg == kTG - 1) s_carry[p ^ 1][d4c] = o;
        }
    };

    for (int it = 0; it < kIters; it += 2) {
        tile(it, v, w);
        tile(it + 1, w, v);
    }
}

extern "C" void kernel_launch(void* const* d_in, const int* in_sizes, int n_in,
                              void* d_out, int out_size, void* d_ws, size_t ws_size,
                              hipStream_t stream) {
    const float* x     = (const float*)d_in[0];
    const float* gamma = (const float*)d_in[1];
    float* y = (float*)d_out;
    dscan_kernel<<<kBH * 4, kThreads, 0, stream>>>(x, gamma, y);
}